// Round 14
// baseline (61.638 us; speedup 1.0000x reference)
//
#include <hip/hip_runtime.h>
#include <cstdint>

#define B8   8
#define DIN  1024
#define NH1  2048
#define NH2  1024
#define NOUT 5120
#define TKS  5      // tropical k-split (5120 = 5 * 1024)

__device__ __forceinline__ float4 ld4(const float* p) {
  return *reinterpret_cast<const float4*>(p);
}
__device__ __forceinline__ void st4(float* p, float4 v) {
  *reinterpret_cast<float4*>(p) = v;
}

// C_parts[kb][8][N] = A[8, k0:k0+KC] @ W[k0:k0+KC, :]   (partial over K-chunk)
template<int K, int N, int KSPLIT, int NPART, bool RELU_IN, bool WRITE_STAGE>
__global__ __launch_bounds__(256)
void gemm8(const float* __restrict__ Asrc, const float* __restrict__ bias_in,
           const float* __restrict__ W, float* __restrict__ Cparts,
           float* __restrict__ stage_out)
{
  constexpr int KC    = K / KSPLIT;
  constexpr int KC4   = KC / 4;
  constexpr int NCOLB = N / 64;
  constexpr int KT    = KC / 16;

  __shared__ float A_lds[8][KC];
  __shared__ float red[16][8][64];

  const int tid = threadIdx.x;
  const int kb  = blockIdx.x / NCOLB;
  const int cb  = blockIdx.x % NCOLB;
  const int k0  = kb * KC;

  for (int e = tid; e < 8 * KC4; e += 256) {
    const int b = e / KC4, k4 = e - b * KC4;
    float4 v;
    if constexpr (NPART == 0) {
      v = ld4(&Asrc[(size_t)b * K + k0 + 4 * k4]);
    } else {
      v = ld4(&bias_in[k0 + 4 * k4]);
      #pragma unroll
      for (int p = 0; p < NPART; ++p) {
        float4 t = ld4(&Asrc[((size_t)p * 8 + b) * K + k0 + 4 * k4]);
        v.x += t.x; v.y += t.y; v.z += t.z; v.w += t.w;
      }
      if constexpr (RELU_IN) {
        v.x = fmaxf(v.x, 0.f); v.y = fmaxf(v.y, 0.f);
        v.z = fmaxf(v.z, 0.f); v.w = fmaxf(v.w, 0.f);
      }
    }
    st4(&A_lds[b][4 * k4], v);
    if constexpr (WRITE_STAGE) {
      if (cb == 0) st4(&stage_out[(size_t)b * K + k0 + 4 * k4], v);
    }
  }
  __syncthreads();

  const int g  = tid & 15, ks = tid >> 4;
  const int c0 = cb * 64 + g * 4;
  float4 acc[8];
  #pragma unroll
  for (int b = 0; b < 8; ++b) acc[b] = make_float4(0.f, 0.f, 0.f, 0.f);

  const float* Wp = &W[(size_t)(k0 + ks * KT) * N + c0];
  #pragma unroll
  for (int i = 0; i < KT; i += 4) {
    const float4 w0 = ld4(Wp + (size_t)(i + 0) * N);
    const float4 w1 = ld4(Wp + (size_t)(i + 1) * N);
    const float4 w2 = ld4(Wp + (size_t)(i + 2) * N);
    const float4 w3 = ld4(Wp + (size_t)(i + 3) * N);
    const int kk = ks * KT + i;
    #pragma unroll
    for (int b = 0; b < 8; ++b) {
      const float4 a = ld4(&A_lds[b][kk]);
      acc[b].x += a.x * w0.x + a.y * w1.x + a.z * w2.x + a.w * w3.x;
      acc[b].y += a.x * w0.y + a.y * w1.y + a.z * w2.y + a.w * w3.y;
      acc[b].z += a.x * w0.z + a.y * w1.z + a.z * w2.z + a.w * w3.z;
      acc[b].w += a.x * w0.w + a.y * w1.w + a.z * w2.w + a.w * w3.w;
    }
  }

  __syncthreads();
  #pragma unroll
  for (int b = 0; b < 8; ++b) st4(&red[ks][b][g * 4], acc[b]);
  __syncthreads();

  for (int p = tid; p < 512; p += 256) {
    const int c = p & 63, b = p >> 6;
    float s = 0.f;
    #pragma unroll
    for (int j = 0; j < 16; ++j) s += red[j][b][c];
    Cparts[((size_t)kb * 8 + b) * N + cb * 64 + c] = s;
  }
}

// logits[8][5120] = sum of 4 partials + b3
__global__ __launch_bounds__(256)
void finalize_logits(const float* __restrict__ parts, const float* __restrict__ b3,
                     float* __restrict__ logits)
{
  const int i  = blockIdx.x * 256 + threadIdx.x;
  const int b  = i / 1280, k4 = i - b * 1280;
  float4 v = ld4(&b3[4 * k4]);
  #pragma unroll
  for (int p = 0; p < 4; ++p) {
    const float4 t = ld4(&parts[((size_t)p * 8 + b) * NOUT + 4 * k4]);
    v.x += t.x; v.y += t.y; v.z += t.z; v.w += t.w;
  }
  st4(&logits[(size_t)b * NOUT + 4 * k4], v);
}

// One row's compute+reduce from named regs C0..C3 against LDS logits.
#define TROP_ROW(C0, C1, C2, C3, ROW)                                   \
  {                                                                     \
    float pm[8];                                                        \
    _Pragma("unroll")                                                   \
    for (int b = 0; b < 8; ++b) pm[b] = -3.402823466e38f;               \
    _Pragma("unroll")                                                   \
    for (int b = 0; b < 8; ++b) {                                       \
      const float4 v0 = ld4(&LgL[b][4 * l]);                            \
      const float4 v1 = ld4(&LgL[b][4 * l + 256]);                      \
      const float4 v2 = ld4(&LgL[b][4 * l + 512]);                      \
      const float4 v3 = ld4(&LgL[b][4 * l + 768]);                      \
      float m0, m1;                                                     \
      m0 = fmaxf(v0.x * C0.x, v0.y * C0.y);                             \
      m1 = fmaxf(v0.z * C0.z, v0.w * C0.w);                             \
      pm[b] = fmaxf(pm[b], fmaxf(m0, m1));                              \
      m0 = fmaxf(v1.x * C1.x, v1.y * C1.y);                             \
      m1 = fmaxf(v1.z * C1.z, v1.w * C1.w);                             \
      pm[b] = fmaxf(pm[b], fmaxf(m0, m1));                              \
      m0 = fmaxf(v2.x * C2.x, v2.y * C2.y);                             \
      m1 = fmaxf(v2.z * C2.z, v2.w * C2.w);                             \
      pm[b] = fmaxf(pm[b], fmaxf(m0, m1));                              \
      m0 = fmaxf(v3.x * C3.x, v3.y * C3.y);                             \
      m1 = fmaxf(v3.z * C3.z, v3.w * C3.w);                             \
      pm[b] = fmaxf(pm[b], fmaxf(m0, m1));                              \
    }                                                                   \
    _Pragma("unroll")                                                   \
    for (int b = 0; b < 8; ++b) {                                       \
      float v = pm[b];                                                  \
      for (int m = 32; m; m >>= 1) v = fmaxf(v, __shfl_xor(v, m));      \
      if (l == 0) tp[(size_t)b * NOUT + (ROW)] = v;                     \
    }                                                                   \
  }

// tpart[ks][b][o] = max_{k in chunk ks} logits[b][k] * CM[o][k]
// DEPTH-2 PING-PONG ON CM: R12's LDS-logits structure, but the next row's
// 4 CM loads (named float4s a0..a3 / b0..b3, 32 VGPR) are ISSUED BEFORE the
// current row's ~900-cycle LDS+VALU compute -- global latency lands under
// compute instead of serializing (the R0-R12 failure mode: compiler
// register-minimizes to 1 outstanding load). ~70 VGPR total, no spill.
// Each CM byte read exactly once chip-wide (disjoint (bx,ks) tiles).
__global__ __launch_bounds__(256)
void tropical_pp(const float* __restrict__ logits, const float* __restrict__ CM,
                 float* __restrict__ tpart)
{
  __shared__ float LgL[8][1024];   // 32 KB logits chunk

  const int tid = threadIdx.x;
  const int w   = tid >> 6;      // wave 0..3
  const int l   = tid & 63;      // lane
  const int ks  = blockIdx.y;    // k-chunk 0..4
  const int k0  = ks * 1024;
  const int o0w = blockIdx.x * 16 + w * 4;   // wave's 4 rows

  // stage logits chunk once (coalesced), single barrier
  #pragma unroll
  for (int it = 0; it < 8; ++it) {
    const int e = tid + 256 * it;
    const int b = e >> 8, k4 = e & 255;
    st4(&LgL[b][4 * k4], ld4(&logits[(size_t)b * NOUT + k0 + 4 * k4]));
  }
  __syncthreads();

  const float* cm0 = &CM[(size_t)o0w * NOUT + k0 + 4 * l];
  float* tp = &tpart[(size_t)ks * 8 * NOUT];

  // prologue: row 0 -> A buffer
  float4 a0 = ld4(cm0), a1 = ld4(cm0 + 256), a2 = ld4(cm0 + 512), a3 = ld4(cm0 + 768);
  float4 b0, b1, b2, b3;

  // row 0: prefetch row 1 -> B, compute row 0 from A
  {
    const float* c = cm0 + (size_t)1 * NOUT;
    b0 = ld4(c); b1 = ld4(c + 256); b2 = ld4(c + 512); b3 = ld4(c + 768);
    TROP_ROW(a0, a1, a2, a3, o0w + 0)
  }
  // row 1: prefetch row 2 -> A, compute row 1 from B
  {
    const float* c = cm0 + (size_t)2 * NOUT;
    a0 = ld4(c); a1 = ld4(c + 256); a2 = ld4(c + 512); a3 = ld4(c + 768);
    TROP_ROW(b0, b1, b2, b3, o0w + 1)
  }
  // row 2: prefetch row 3 -> B, compute row 2 from A
  {
    const float* c = cm0 + (size_t)3 * NOUT;
    b0 = ld4(c); b1 = ld4(c + 256); b2 = ld4(c + 512); b3 = ld4(c + 768);
    TROP_ROW(a0, a1, a2, a3, o0w + 2)
  }
  // row 3: compute from B
  TROP_ROW(b0, b1, b2, b3, o0w + 3)
}

// out[b][o] = max_ks tpart[ks][b][o]
__global__ __launch_bounds__(256)
void tropical_combine(const float* __restrict__ tpart, float* __restrict__ out)
{
  const int i = blockIdx.x * 256 + threadIdx.x;
  float4 v = ld4(&tpart[4 * (size_t)i]);
  #pragma unroll
  for (int p = 1; p < TKS; ++p) {
    const float4 t = ld4(&tpart[(size_t)p * 8 * NOUT + 4 * (size_t)i]);
    v.x = fmaxf(v.x, t.x); v.y = fmaxf(v.y, t.y);
    v.z = fmaxf(v.z, t.z); v.w = fmaxf(v.w, t.w);
  }
  st4(&out[4 * (size_t)i], v);
}

extern "C" void kernel_launch(void* const* d_in, const int* in_sizes, int n_in,
                              void* d_out, int out_size, void* d_ws, size_t ws_size,
                              hipStream_t stream)
{
  const float* x  = (const float*)d_in[0];
  const float* W1 = (const float*)d_in[1];
  const float* b1 = (const float*)d_in[2];
  const float* W2 = (const float*)d_in[3];
  const float* b2 = (const float*)d_in[4];
  const float* W3 = (const float*)d_in[5];
  const float* b3 = (const float*)d_in[6];
  const float* CM = (const float*)d_in[7];

  float* out  = (float*)d_out;            // [8][5120]
  float* feat = out + B8 * NOUT;          // [8][1024]

  float* ws      = (float*)d_ws;
  float* parts1  = ws;                      // [ 8][8][2048] = 131072 f
  float* parts2  = parts1 + 8  * 8 * NH1;   // [16][8][1024] = 131072 f
  float* parts3  = parts2 + 16 * 8 * NH2;   // [ 4][8][5120] = 163840 f
  float* logits  = parts3 + 4  * 8 * NOUT;  // [8][5120]     =  40960 f
  float* tpart   = logits + 8 * NOUT;       // [5][8][5120]  = 204800 f

  gemm8<DIN, NH1, 8, 0, false, false><<<256, 256, 0, stream>>>(x, nullptr, W1, parts1, nullptr);
  gemm8<NH1, NH2, 16, 8, true, false><<<256, 256, 0, stream>>>(parts1, b1, W2, parts2, nullptr);
  gemm8<NH2, NOUT, 4, 16, true, true><<<320, 256, 0, stream>>>(parts2, b2, W3, parts3, feat);
  finalize_logits<<<40, 256, 0, stream>>>(parts3, b3, logits);
  {
    dim3 grid(320, TKS);
    tropical_pp<<<grid, 256, 0, stream>>>(logits, CM, tpart);
  }
  tropical_combine<<<40, 256, 0, stream>>>(tpart, out);
}